// Round 19
// baseline (118.098 us; speedup 1.0000x reference)
//
#include <hip/hip_runtime.h>
#include <math.h>

#define BB 2
#define NN 2048
#define HD 256
#define NH 8
#define DH 32
#define NTOK (BB*NN)   // 4096
#define QKVLD 768      // fused qkv row stride (fp16)
#define NSPLIT 2       // split-KV ways
#define KVPB (NN/NSPLIT)   // 1024 kv per block
#define NTILES (KVPB/64)   // 16

typedef _Float16 h8 __attribute__((ext_vector_type(8)));
typedef _Float16 h4 __attribute__((ext_vector_type(4)));
typedef float fx4 __attribute__((ext_vector_type(4)));

#define LOG2E 1.4426950408889634f
#define SQ_LOG2 0.25503486f   // log2(e)/sqrt(32), folded into wq/bq
// static-max softmax: P = exp2(st + 2*LOG2E*a - LOG2E - 6); bounded by construction.
#define C1A (2.0f * LOG2E)
#define C0A (-(LOG2E + 6.0f))

// ---------------- LayerNorm row helper ----------------
__device__ __forceinline__ void ln_row(const float* __restrict__ x,
    const float* __restrict__ g, const float* __restrict__ bta,
    _Float16* __restrict__ yh, int row, int lane)
{
  const float* xr = x + (size_t)row * HD + lane * 4;
  float4 v = *(const float4*)xr;
  float s = v.x + v.y + v.z + v.w;
  #pragma unroll
  for (int off = 32; off > 0; off >>= 1) s += __shfl_xor(s, off);
  float mu = s * (1.0f / HD);
  float dx0 = v.x - mu, dx1 = v.y - mu, dx2 = v.z - mu, dx3 = v.w - mu;
  float ss = dx0*dx0 + dx1*dx1 + dx2*dx2 + dx3*dx3;
  #pragma unroll
  for (int off = 32; off > 0; off >>= 1) ss += __shfl_xor(ss, off);
  float rinv = rsqrtf(ss * (1.0f / HD) + 1e-5f);
  float4 gv = *(const float4*)(g   + lane * 4);
  float4 bv = *(const float4*)(bta + lane * 4);
  h4 hh;
  hh[0] = (_Float16)(dx0 * rinv * gv.x + bv.x);
  hh[1] = (_Float16)(dx1 * rinv * gv.y + bv.y);
  hh[2] = (_Float16)(dx2 * rinv * gv.z + bv.z);
  hh[3] = (_Float16)(dx3 * rinv * gv.w + bv.w);
  *(h4*)(yh + (size_t)row * HD + lane * 4) = hh;
}

__global__ __launch_bounds__(256) void ln_kernel(const float* __restrict__ x,
    const float* __restrict__ g, const float* __restrict__ bta,
    _Float16* __restrict__ yh)
{
  ln_row(x, g, bta, yh, blockIdx.x * 4 + (threadIdx.x >> 6), threadIdx.x & 63);
}

// ---------------- fused prep: weight transposes + bias concat + LN1 -------
__device__ __forceinline__ void do_transpose(const float* __restrict__ W,
    _Float16* __restrict__ Wh, int Nw, int rowoff, int ldout, float scale,
    int bx, int by, float (*tile)[33])
{
  int k0 = by * 32, n0 = bx * 32;
  int c = threadIdx.x & 31, r = threadIdx.x >> 5;   // r 0..7
  #pragma unroll
  for (int i = 0; i < 4; i++)
    tile[r + i * 8][c] = W[(size_t)(k0 + r + i * 8) * Nw + n0 + c];
  __syncthreads();
  #pragma unroll
  for (int i = 0; i < 4; i++) {
    int n = r + i * 8;
    Wh[(size_t)(rowoff + n0 + n) * ldout + k0 + c] = (_Float16)(tile[c][n] * scale);
  }
}

__global__ __launch_bounds__(256) void prep_kernel(
    const float* wq, const float* wk, const float* wv, const float* wo,
    const float* wf1, const float* wf2,
    const float* bq, const float* bk, const float* bv,
    const float* hidden, const float* g1, const float* b1,
    _Float16* WtQKVh, _Float16* WtOh, _Float16* WtF1h, _Float16* WtF2h,
    float* biasqkv, _Float16* norm1h)
{
  __shared__ float tile[32][33];
  int bid = blockIdx.x;
  if (bid < 64)        do_transpose(wq,  WtQKVh,  256,   0,  256, SQ_LOG2, bid & 7, bid >> 3, tile);
  else if (bid < 128)  do_transpose(wk,  WtQKVh,  256, 256,  256, 1.0f, (bid-64) & 7, (bid-64) >> 3, tile);
  else if (bid < 192)  do_transpose(wv,  WtQKVh,  256, 512,  256, 1.0f, (bid-128) & 7, (bid-128) >> 3, tile);
  else if (bid < 256)  do_transpose(wo,  WtOh,    256,   0,  256, 1.0f, (bid-192) & 7, (bid-192) >> 3, tile);
  else if (bid < 512)  do_transpose(wf1, WtF1h,  1024,   0,  256, 1.0f, (bid-256) & 31, (bid-256) >> 5, tile);
  else if (bid < 768)  do_transpose(wf2, WtF2h,   256,   0, 1024, 1.0f, (bid-512) & 7, (bid-512) >> 3, tile);
  else if (bid == 768) {
    #pragma unroll
    for (int j = 0; j < 3; j++) {
      int t = j * 256 + threadIdx.x;
      biasqkv[t] = (t < 256) ? bq[t] * SQ_LOG2 : (t < 512) ? bk[t - 256] : bv[t - 512];
    }
  } else {
    // LN1: blocks 769..1792 -> 4096 rows
    ln_row(hidden, g1, b1, norm1h, (bid - 769) * 4 + (threadIdx.x >> 6), threadIdx.x & 63);
  }
}

// ---------------- pure-fp16 MFMA GEMM, direct-fragment, XCD-bijective swizzle,
// 2-stage register pipeline (issue k+1 loads before k's MFMAs: 2x memory-level
// parallelism at identical traffic -- GEMMs are latency-bound at MfmaUtil ~5%) ----
template<int KK, int NT, int NX, int ACT, int RES, int OM>
__global__ __launch_bounds__(256) void gemm16_kernel(
    const _Float16* __restrict__ Ah, const _Float16* __restrict__ Wh,
    const float* __restrict__ bias, const float* __restrict__ resid,
    float* __restrict__ Cf, _Float16* __restrict__ Ch,
    _Float16* __restrict__ vtb, int N)
{
  const int lin = blockIdx.x;
  const int qch = gridDim.x >> 3;
  const int wg = (lin & 7) * qch + (lin >> 3);   // bijective (nwg % 8 == 0)
  const int bx = wg % NX, by = wg / NX;
  const int n0 = bx * (NT * 16);
  const int m0 = by * 64;
  const int t = threadIdx.x, w = t >> 6, l = t & 63;
  const int ml = l & 15, g = l >> 4;
  const int mrow = m0 + w * 16 + ml;

  const _Float16* aph = Ah + (size_t)mrow * KK + g * 8;
  const _Float16* whp[NT];
  #pragma unroll
  for (int nt = 0; nt < NT; nt++)
    whp[nt] = Wh + (size_t)(n0 + nt * 16 + ml) * KK + g * 8;

  fx4 acc[NT];
  #pragma unroll
  for (int nt = 0; nt < NT; nt++) acc[nt] = (fx4){0.f, 0.f, 0.f, 0.f};

  // software pipeline: stage 0 loads
  h8 ah = *(const h8*)(aph);
  h8 wh[NT];
  #pragma unroll
  for (int nt = 0; nt < NT; nt++) wh[nt] = *(const h8*)(whp[nt]);

  #pragma unroll 2
  for (int k0 = 32; k0 <= KK; k0 += 32) {
    h8 ahn;
    h8 whn[NT];
    if (k0 < KK) {
      ahn = *(const h8*)(aph + k0);
      #pragma unroll
      for (int nt = 0; nt < NT; nt++) whn[nt] = *(const h8*)(whp[nt] + k0);
    }
    #pragma unroll
    for (int nt = 0; nt < NT; nt++)
      acc[nt] = __builtin_amdgcn_mfma_f32_16x16x32_f16(ah, wh[nt], acc[nt], 0, 0, 0);
    ah = ahn;
    #pragma unroll
    for (int nt = 0; nt < NT; nt++) wh[nt] = whn[nt];
  }

  #pragma unroll
  for (int nt = 0; nt < NT; nt++) {
    int n = n0 + nt * 16 + ml;
    float bv = bias[n];
    #pragma unroll
    for (int i = 0; i < 4; i++) {
      int m = m0 + w * 16 + 4 * g + i;
      float vv = acc[nt][i] + bv;
      if (ACT == 1) vv = 0.5f * vv * (1.0f + erff(vv * 0.70710678118654752f));
      if (RES)      vv += resid[(size_t)m * N + n];
      if (OM == 0) {
        Cf[(size_t)m * N + n] = vv;
      } else if (OM == 1) {
        Ch[(size_t)m * N + n] = (_Float16)vv;
      } else {   // OM == 2: qkv; V transposed with pair-interleaved kv index
        if (n < 512) Ch[(size_t)m * QKVLD + n] = (_Float16)vv;
        else {
          int dim = n - 512, kv = m & (NN - 1), bb = m >> 11;
          int kvp = (kv & ~31) | ((kv & 15) << 1) | ((kv >> 4) & 1);
          vtb[((size_t)(bb * HD + dim)) * NN + kvp] = (_Float16)vv;
        }
      }
    }
  }
}

// ---------------- WO GEMM with FUSED split-KV combine ----------------
__global__ __launch_bounds__(256) void wo_fused_kernel(
    const _Float16* __restrict__ Opart, const float* __restrict__ Spart,
    const _Float16* __restrict__ Wh, const float* __restrict__ bias,
    const float* __restrict__ resid, float* __restrict__ Cf)
{
  const int lin = blockIdx.x;                  // 512 blocks
  const int qch = gridDim.x >> 3;
  const int wg = (lin & 7) * qch + (lin >> 3);
  const int bx = wg & 7, by = wg >> 3;         // NX=8
  const int n0 = bx * 32;
  const int m0 = by * 64;
  const int t = threadIdx.x, w = t >> 6, l = t & 63;
  const int ml = l & 15, g = l >> 4;
  const int mrow = m0 + w * 16 + ml;
  const int bb = mrow >> 11, qrow = mrow & (NN - 1);

  const _Float16* whp0 = Wh + (size_t)(n0 + ml) * HD + g * 8;
  const _Float16* whp1 = Wh + (size_t)(n0 + 16 + ml) * HD + g * 8;

  fx4 acc0 = {0.f, 0.f, 0.f, 0.f};
  fx4 acc1 = {0.f, 0.f, 0.f, 0.f};

  #pragma unroll
  for (int h = 0; h < NH; h++) {
    size_t p0 = ((size_t)((bb * 2 + 0) * NH + h)) * NN + qrow;
    size_t p1 = ((size_t)((bb * 2 + 1) * NH + h)) * NN + qrow;
    float s0 = Spart[p0], s1 = Spart[p1];
    float den = 1.0f / (s0 + s1);
    float w0 = s0 * den, w1 = s1 * den;
    h8 o0 = *(const h8*)(Opart + p0 * 32 + g * 8);
    h8 o1 = *(const h8*)(Opart + p1 * 32 + g * 8);
    h8 ah;
    #pragma unroll
    for (int j = 0; j < 8; j++)
      ah[j] = (_Float16)(w0 * (float)o0[j] + w1 * (float)o1[j]);
    h8 wh0 = *(const h8*)(whp0 + h * 32);
    h8 wh1 = *(const h8*)(whp1 + h * 32);
    acc0 = __builtin_amdgcn_mfma_f32_16x16x32_f16(ah, wh0, acc0, 0, 0, 0);
    acc1 = __builtin_amdgcn_mfma_f32_16x16x32_f16(ah, wh1, acc1, 0, 0, 0);
  }

  #pragma unroll
  for (int i = 0; i < 4; i++) {
    int m = m0 + w * 16 + 4 * g + i;
    int na = n0 + ml, nb = n0 + 16 + ml;
    Cf[(size_t)m * HD + na] = acc0[i] + bias[na] + resid[(size_t)m * HD + na];
    Cf[(size_t)m * HD + nb] = acc1[i] + bias[nb] + resid[(size_t)m * HD + nb];
  }
}

// ---------------- MFMA flash attention: 4 HEADS PER 1024-THREAD BLOCK ----------
// Waves 4h..4h+3 = head hg*4+h; each head has a private single-buffered K/V
// LDS slice; the 64x64 adjacency tile is staged ONCE per block and shared by
// all 4 heads -> adj traffic 2 reads/elem -> 1 read per 4 heads. 2 barriers
// per tile (r11 showed barrier count is non-binding). Static-max softmax.
// LDS: K 20KB + V 18KB + adj 8.5KB = 47.6KB < 64KB.
__global__ __launch_bounds__(1024) void attn_mfma_kernel(
    const _Float16* __restrict__ qkv16, const _Float16* __restrict__ vtb,
    const float* __restrict__ adj,
    _Float16* __restrict__ Opart, float* __restrict__ Spart)
{
  __shared__ _Float16 Ksh[4][64][40];   // [head][kv][dim]   20.5 KB
  __shared__ _Float16 Vp[4][32][72];    // [head][dim][kv']  18.4 KB
  __shared__ _Float16 AdjL[64][68];     // [qrow][kv] shared  8.7 KB

  const int z = blockIdx.z;                  // b*NSPLIT + half (0..3)
  const int b = z >> 1, half = z & 1;
  const int hg = blockIdx.y;                 // head group (0..1)
  const int q0 = blockIdx.x * 64;
  const int t = threadIdx.x;                 // 0..1023
  const int hh_ = t >> 8;                    // head within block (0..3)
  const int head = hg * 4 + hh_;
  const int tl = t & 255;
  const int w = tl >> 6, l = t & 63;
  const int m = l & 15, g = l >> 4;
  const int kvbase = half * KVPB;            // 1024 kv per block

  const int qrow = q0 + w * 16 + m;
  h8 qh = *(const h8*)(qkv16 + ((size_t)(b * NN + qrow)) * QKVLD + head * DH + g * 8);

  fx4 ot0 = {0.f, 0.f, 0.f, 0.f};
  fx4 ot1 = {0.f, 0.f, 0.f, 0.f};
  float S4[4] = {0.f, 0.f, 0.f, 0.f};

  // shared adj staging: 1024 threads, 1 float4 each: row t>>4 (0..63), col (t&15)*4
  const int arow = t >> 4;
  const int acol = (t & 15) * 4;
  const float* adjbase = adj + ((size_t)(b * NN + q0)) * NN + kvbase;

  const int krow = tl >> 2, kd0 = (tl & 3) * 8;   // K staging role (within head)
  const int vdim = tl >> 3, vkc = (tl & 7) * 8;   // V' staging role
  const _Float16* kbase = qkv16 + ((size_t)(b * NN + kvbase + krow)) * QKVLD + 256 + head * DH + kd0;
  const _Float16* vbase = vtb + ((size_t)(b * HD + head * DH + vdim)) * NN + kvbase + vkc;

  h8 kreg = *(const h8*)kbase;
  h8 vreg = *(const h8*)vbase;
  float4 areg = *(const float4*)(adjbase + (size_t)arow * NN + acol);

  for (int tt = 0; tt < NTILES; ++tt) {
    // ---- stage tile tt (regs -> LDS) ----
    *(h8*)&Ksh[hh_][krow][kd0] = kreg;
    *(h8*)&Vp[hh_][vdim][vkc]  = vreg;
    {
      h4 hh;
      hh[0] = (_Float16)areg.x; hh[1] = (_Float16)areg.y;
      hh[2] = (_Float16)areg.z; hh[3] = (_Float16)areg.w;
      *(h4*)&AdjL[arow][acol] = hh;
    }
    __syncthreads();

    // ---- issue tile tt+1 loads (hide under compute) ----
    if (tt + 1 < NTILES) {
      kreg = *(const h8*)(kbase + (size_t)((tt + 1) * 64) * QKVLD);
      vreg = *(const h8*)(vbase + (tt + 1) * 64);
      areg = *(const float4*)(adjbase + (size_t)arow * NN + (tt + 1) * 64 + acol);
    }

    // ---- QK^T for the 64-kv tile ----
    h8 kh0 = *(const h8*)&Ksh[hh_][     m][g * 8];
    h8 kh1 = *(const h8*)&Ksh[hh_][16 + m][g * 8];
    h8 kh2 = *(const h8*)&Ksh[hh_][32 + m][g * 8];
    h8 kh3 = *(const h8*)&Ksh[hh_][48 + m][g * 8];
    fx4 z4 = {0.f, 0.f, 0.f, 0.f};
    fx4 st[4];
    st[0] = __builtin_amdgcn_mfma_f32_16x16x32_f16(kh0, qh, z4, 0, 0, 0);
    st[1] = __builtin_amdgcn_mfma_f32_16x16x32_f16(kh1, qh, z4, 0, 0, 0);
    st[2] = __builtin_amdgcn_mfma_f32_16x16x32_f16(kh2, qh, z4, 0, 0, 0);
    st[3] = __builtin_amdgcn_mfma_f32_16x16x32_f16(kh3, qh, z4, 0, 0, 0);

    // ---- adj from shared LDS (h4 reads), static-max softmax ----
    float pv[16];
    #pragma unroll
    for (int p = 0; p < 4; p++) {
      h4 ah4 = *(const h4*)&AdjL[w * 16 + m][p * 16 + g * 4];
      float ps = 0.f;
      #pragma unroll
      for (int i = 0; i < 4; i++) {
        float a = (float)ah4[i];
        float e = __builtin_amdgcn_exp2f(st[p][i] + C1A * a + C0A);
        float pp = (0.25f + 0.75f * a) * e;
        pv[p * 4 + i] = pp;
        ps += pp;
      }
      S4[p] += ps;
    }
    // pack P in pair-interleaved k-slot order
    h8 ph0, ph1;
    #pragma unroll
    for (int q2 = 0; q2 < 4; q2++) {
      ph0[2*q2]     = (_Float16)pv[q2];
      ph0[2*q2 + 1] = (_Float16)pv[4 + q2];
      ph1[2*q2]     = (_Float16)pv[8 + q2];
      ph1[2*q2 + 1] = (_Float16)pv[12 + q2];
    }

    // ---- PV ----
    h8 v00 = *(const h8*)&Vp[hh_][m][g * 8];
    h8 v01 = *(const h8*)&Vp[hh_][m][32 + g * 8];
    h8 v10 = *(const h8*)&Vp[hh_][16 + m][g * 8];
    h8 v11 = *(const h8*)&Vp[hh_][16 + m][32 + g * 8];
    ot0 = __builtin_amdgcn_mfma_f32_16x16x32_f16(v00, ph0, ot0, 0, 0, 0);
    ot0 = __builtin_amdgcn_mfma_f32_16x16x32_f16(v01, ph1, ot0, 0, 0, 0);
    ot1 = __builtin_amdgcn_mfma_f32_16x16x32_f16(v10, ph0, ot1, 0, 0, 0);
    ot1 = __builtin_amdgcn_mfma_f32_16x16x32_f16(v11, ph1, ot1, 0, 0, 0);

    __syncthreads();   // all compute reads done before next stage overwrites
  }

  // denominator: tree-combine the 4 partials, then cross-lane reduce
  float S = (S4[0] + S4[1]) + (S4[2] + S4[3]);
  S += __shfl_xor(S, 16);
  S += __shfl_xor(S, 32);

  float is = 1.0f / S;
  size_t prow = ((size_t)(z * NH + head)) * NN + qrow;
  _Float16* po = Opart + prow * 32;
  h4 o0h, o1h;
  #pragma unroll
  for (int j = 0; j < 4; j++) {
    o0h[j] = (_Float16)(ot0[j] * is);
    o1h[j] = (_Float16)(ot1[j] * is);
  }
  *(h4*)(po + 4 * g)      = o0h;
  *(h4*)(po + 16 + 4 * g) = o1h;
  if (g == 0) Spart[prow] = S;
}

extern "C" void kernel_launch(void* const* d_in, const int* in_sizes, int n_in,
                              void* d_out, int out_size, void* d_ws, size_t ws_size,
                              hipStream_t stream)
{
  const float* hidden    = (const float*)d_in[0];
  const float* adjacency = (const float*)d_in[1];
  const float* wq  = (const float*)d_in[3];
  const float* bq  = (const float*)d_in[4];
  const float* wk  = (const float*)d_in[5];
  const float* bk  = (const float*)d_in[6];
  const float* wv  = (const float*)d_in[7];
  const float* bv  = (const float*)d_in[8];
  const float* wo  = (const float*)d_in[9];
  const float* bo  = (const float*)d_in[10];
  const float* g1  = (const float*)d_in[11];
  const float* b1  = (const float*)d_in[12];
  const float* g2  = (const float*)d_in[13];
  const float* b2  = (const float*)d_in[14];
  const float* wf1 = (const float*)d_in[15];
  const float* bf1 = (const float*)d_in[16];
  const float* wf2 = (const float*)d_in[17];
  const float* bf2 = (const float*)d_in[18];
  float* out = (float*)d_out;

  char* base = (char*)d_ws;
  const size_t MB = 1024 * 1024;
  _Float16* norm1h = (_Float16*)(base);          // [0,2)
  _Float16* qkv16  = (_Float16*)(base + 2*MB);   // [2,8): [4096][768]
  _Float16* vtb    = (_Float16*)(base + 8*MB);   // [8,10): [2][256][2048]
  float*    hid2   = (float*)(base + 12*MB);     // [12,16) f32
  // attn fp16 partials [16,20.2); ffah overlays [16,24) after WO consumed them:
  _Float16* Opart = (_Float16*)(base + 16*MB);   // 4.2 MB: [4][8][2048][32] fp16
  _Float16* ffah  = (_Float16*)(base + 16*MB);   // [16,24): [4096][1024]
  float* Spart = (float*)(base + 25*MB);         // 512 KB: [4][8][2048] f32
  _Float16* wtb = (_Float16*)(base + 26*MB);     // 1.5 MB weights
  _Float16* WtQKVh = wtb; wtb += 768 * 256;
  _Float16* WtOh   = wtb; wtb += 256 * 256;
  _Float16* WtF1h  = wtb; wtb += 1024 * 256;
  _Float16* WtF2h  = wtb; wtb += 256 * 1024;
  float* biasqkv = (float*)(base + 28*MB);

  // prep: weight transposes + bias concat + LN1 (blocks 769..1792)
  prep_kernel<<<1793, 256, 0, stream>>>(wq, wk, wv, wo, wf1, wf2, bq, bk, bv,
      hidden, g1, b1, WtQKVh, WtOh, WtF1h, WtF2h, biasqkv, norm1h);

  // fused QKV (NT=4, grid 768)
  gemm16_kernel<256, 4, 12, 0, 0, 2><<<768, 256, 0, stream>>>(
      norm1h, WtQKVh, biasqkv, nullptr, nullptr, qkv16, vtb, QKVLD);

  // 4-heads-per-block attention: grid (32 qtiles, 2 head-groups, 4 z), 1024 thr
  attn_mfma_kernel<<<dim3(NN / 64, NH / 4, BB * NSPLIT), 1024, 0, stream>>>(
      qkv16, vtb, adjacency, Opart, Spart);

  // WO GEMM with fused split-KV combine (+ bias + residual)
  wo_fused_kernel<<<512, 256, 0, stream>>>(
      Opart, Spart, WtOh, bo, hidden, hid2);

  ln_kernel<<<NTOK / 4, 256, 0, stream>>>(hid2, g2, b2, norm1h);

  // FF1 (NT=4, grid 1024)
  gemm16_kernel<256, 4, 16, 1, 0, 1><<<1024, 256, 0, stream>>>(
      norm1h, WtF1h, bf1, nullptr, nullptr, ffah, nullptr, 1024);

  // FF2 (NT=2, grid 512)
  gemm16_kernel<1024, 2, 8, 0, 1, 0><<<512, 256, 0, stream>>>(
      ffah, WtF2h, bf2, hid2, out, nullptr, nullptr, 256);
}

// Round 20
// 116.302 us; speedup vs baseline: 1.0154x; 1.0154x over previous
//
#include <hip/hip_runtime.h>
#include <math.h>

#define BB 2
#define NN 2048
#define HD 256
#define NH 8
#define DH 32
#define NTOK (BB*NN)   // 4096
#define QKVLD 768      // fused qkv row stride (fp16)
#define NSPLIT 2       // split-KV ways
#define KVPB (NN/NSPLIT)   // 1024 kv per block
#define NTILES (KVPB/64)   // 16

typedef _Float16 h8 __attribute__((ext_vector_type(8)));
typedef _Float16 h4 __attribute__((ext_vector_type(4)));
typedef float fx4 __attribute__((ext_vector_type(4)));

#define LOG2E 1.4426950408889634f
#define SQ_LOG2 0.25503486f   // log2(e)/sqrt(32), folded into wq/bq
// static-max softmax: P = exp2(st + 2*LOG2E*a - LOG2E - 6); bounded by construction.
#define C1A (2.0f * LOG2E)
#define C0A (-(LOG2E + 6.0f))

// ---------------- LayerNorm row helper ----------------
__device__ __forceinline__ void ln_row(const float* __restrict__ x,
    const float* __restrict__ g, const float* __restrict__ bta,
    _Float16* __restrict__ yh, int row, int lane)
{
  const float* xr = x + (size_t)row * HD + lane * 4;
  float4 v = *(const float4*)xr;
  float s = v.x + v.y + v.z + v.w;
  #pragma unroll
  for (int off = 32; off > 0; off >>= 1) s += __shfl_xor(s, off);
  float mu = s * (1.0f / HD);
  float dx0 = v.x - mu, dx1 = v.y - mu, dx2 = v.z - mu, dx3 = v.w - mu;
  float ss = dx0*dx0 + dx1*dx1 + dx2*dx2 + dx3*dx3;
  #pragma unroll
  for (int off = 32; off > 0; off >>= 1) ss += __shfl_xor(ss, off);
  float rinv = rsqrtf(ss * (1.0f / HD) + 1e-5f);
  float4 gv = *(const float4*)(g   + lane * 4);
  float4 bv = *(const float4*)(bta + lane * 4);
  h4 hh;
  hh[0] = (_Float16)(dx0 * rinv * gv.x + bv.x);
  hh[1] = (_Float16)(dx1 * rinv * gv.y + bv.y);
  hh[2] = (_Float16)(dx2 * rinv * gv.z + bv.z);
  hh[3] = (_Float16)(dx3 * rinv * gv.w + bv.w);
  *(h4*)(yh + (size_t)row * HD + lane * 4) = hh;
}

__global__ __launch_bounds__(256) void ln_kernel(const float* __restrict__ x,
    const float* __restrict__ g, const float* __restrict__ bta,
    _Float16* __restrict__ yh)
{
  ln_row(x, g, bta, yh, blockIdx.x * 4 + (threadIdx.x >> 6), threadIdx.x & 63);
}

// ---------------- fused prep: weight transposes + bias concat + LN1 -------
__device__ __forceinline__ void do_transpose(const float* __restrict__ W,
    _Float16* __restrict__ Wh, int Nw, int rowoff, int ldout, float scale,
    int bx, int by, float (*tile)[33])
{
  int k0 = by * 32, n0 = bx * 32;
  int c = threadIdx.x & 31, r = threadIdx.x >> 5;   // r 0..7
  #pragma unroll
  for (int i = 0; i < 4; i++)
    tile[r + i * 8][c] = W[(size_t)(k0 + r + i * 8) * Nw + n0 + c];
  __syncthreads();
  #pragma unroll
  for (int i = 0; i < 4; i++) {
    int n = r + i * 8;
    Wh[(size_t)(rowoff + n0 + n) * ldout + k0 + c] = (_Float16)(tile[c][n] * scale);
  }
}

__global__ __launch_bounds__(256) void prep_kernel(
    const float* wq, const float* wk, const float* wv, const float* wo,
    const float* wf1, const float* wf2,
    const float* bq, const float* bk, const float* bv,
    const float* hidden, const float* g1, const float* b1,
    _Float16* WtQKVh, _Float16* WtOh, _Float16* WtF1h, _Float16* WtF2h,
    float* biasqkv, _Float16* norm1h)
{
  __shared__ float tile[32][33];
  int bid = blockIdx.x;
  if (bid < 64)        do_transpose(wq,  WtQKVh,  256,   0,  256, SQ_LOG2, bid & 7, bid >> 3, tile);
  else if (bid < 128)  do_transpose(wk,  WtQKVh,  256, 256,  256, 1.0f, (bid-64) & 7, (bid-64) >> 3, tile);
  else if (bid < 192)  do_transpose(wv,  WtQKVh,  256, 512,  256, 1.0f, (bid-128) & 7, (bid-128) >> 3, tile);
  else if (bid < 256)  do_transpose(wo,  WtOh,    256,   0,  256, 1.0f, (bid-192) & 7, (bid-192) >> 3, tile);
  else if (bid < 512)  do_transpose(wf1, WtF1h,  1024,   0,  256, 1.0f, (bid-256) & 31, (bid-256) >> 5, tile);
  else if (bid < 768)  do_transpose(wf2, WtF2h,   256,   0, 1024, 1.0f, (bid-512) & 7, (bid-512) >> 3, tile);
  else if (bid == 768) {
    #pragma unroll
    for (int j = 0; j < 3; j++) {
      int t = j * 256 + threadIdx.x;
      biasqkv[t] = (t < 256) ? bq[t] * SQ_LOG2 : (t < 512) ? bk[t - 256] : bv[t - 512];
    }
  } else {
    // LN1: blocks 769..1792 -> 4096 rows
    ln_row(hidden, g1, b1, norm1h, (bid - 769) * 4 + (threadIdx.x >> 6), threadIdx.x & 63);
  }
}

// ---------------- pure-fp16 MFMA GEMM, direct-fragment, XCD-bijective swizzle,
// 2-stage register pipeline (kept from r19 for this round's A/B) ----
template<int KK, int NT, int NX, int ACT, int RES, int OM>
__global__ __launch_bounds__(256) void gemm16_kernel(
    const _Float16* __restrict__ Ah, const _Float16* __restrict__ Wh,
    const float* __restrict__ bias, const float* __restrict__ resid,
    float* __restrict__ Cf, _Float16* __restrict__ Ch,
    _Float16* __restrict__ vtb, int N)
{
  const int lin = blockIdx.x;
  const int qch = gridDim.x >> 3;
  const int wg = (lin & 7) * qch + (lin >> 3);   // bijective (nwg % 8 == 0)
  const int bx = wg % NX, by = wg / NX;
  const int n0 = bx * (NT * 16);
  const int m0 = by * 64;
  const int t = threadIdx.x, w = t >> 6, l = t & 63;
  const int ml = l & 15, g = l >> 4;
  const int mrow = m0 + w * 16 + ml;

  const _Float16* aph = Ah + (size_t)mrow * KK + g * 8;
  const _Float16* whp[NT];
  #pragma unroll
  for (int nt = 0; nt < NT; nt++)
    whp[nt] = Wh + (size_t)(n0 + nt * 16 + ml) * KK + g * 8;

  fx4 acc[NT];
  #pragma unroll
  for (int nt = 0; nt < NT; nt++) acc[nt] = (fx4){0.f, 0.f, 0.f, 0.f};

  // software pipeline: stage 0 loads
  h8 ah = *(const h8*)(aph);
  h8 wh[NT];
  #pragma unroll
  for (int nt = 0; nt < NT; nt++) wh[nt] = *(const h8*)(whp[nt]);

  #pragma unroll 2
  for (int k0 = 32; k0 <= KK; k0 += 32) {
    h8 ahn;
    h8 whn[NT];
    if (k0 < KK) {
      ahn = *(const h8*)(aph + k0);
      #pragma unroll
      for (int nt = 0; nt < NT; nt++) whn[nt] = *(const h8*)(whp[nt] + k0);
    }
    #pragma unroll
    for (int nt = 0; nt < NT; nt++)
      acc[nt] = __builtin_amdgcn_mfma_f32_16x16x32_f16(ah, wh[nt], acc[nt], 0, 0, 0);
    ah = ahn;
    #pragma unroll
    for (int nt = 0; nt < NT; nt++) wh[nt] = whn[nt];
  }

  #pragma unroll
  for (int nt = 0; nt < NT; nt++) {
    int n = n0 + nt * 16 + ml;
    float bv = bias[n];
    #pragma unroll
    for (int i = 0; i < 4; i++) {
      int m = m0 + w * 16 + 4 * g + i;
      float vv = acc[nt][i] + bv;
      if (ACT == 1) vv = 0.5f * vv * (1.0f + erff(vv * 0.70710678118654752f));
      if (RES)      vv += resid[(size_t)m * N + n];
      if (OM == 0) {
        Cf[(size_t)m * N + n] = vv;
      } else if (OM == 1) {
        Ch[(size_t)m * N + n] = (_Float16)vv;
      } else {   // OM == 2: qkv; V transposed with pair-interleaved kv index
        if (n < 512) Ch[(size_t)m * QKVLD + n] = (_Float16)vv;
        else {
          int dim = n - 512, kv = m & (NN - 1), bb = m >> 11;
          int kvp = (kv & ~31) | ((kv & 15) << 1) | ((kv >> 4) & 1);
          vtb[((size_t)(bb * HD + dim)) * NN + kvp] = (_Float16)vv;
        }
      }
    }
  }
}

// ---------------- WO GEMM with FUSED split-KV combine ----------------
__global__ __launch_bounds__(256) void wo_fused_kernel(
    const _Float16* __restrict__ Opart, const float* __restrict__ Spart,
    const _Float16* __restrict__ Wh, const float* __restrict__ bias,
    const float* __restrict__ resid, float* __restrict__ Cf)
{
  const int lin = blockIdx.x;                  // 512 blocks
  const int qch = gridDim.x >> 3;
  const int wg = (lin & 7) * qch + (lin >> 3);
  const int bx = wg & 7, by = wg >> 3;         // NX=8
  const int n0 = bx * 32;
  const int m0 = by * 64;
  const int t = threadIdx.x, w = t >> 6, l = t & 63;
  const int ml = l & 15, g = l >> 4;
  const int mrow = m0 + w * 16 + ml;
  const int bb = mrow >> 11, qrow = mrow & (NN - 1);

  const _Float16* whp0 = Wh + (size_t)(n0 + ml) * HD + g * 8;
  const _Float16* whp1 = Wh + (size_t)(n0 + 16 + ml) * HD + g * 8;

  fx4 acc0 = {0.f, 0.f, 0.f, 0.f};
  fx4 acc1 = {0.f, 0.f, 0.f, 0.f};

  #pragma unroll
  for (int h = 0; h < NH; h++) {
    size_t p0 = ((size_t)((bb * 2 + 0) * NH + h)) * NN + qrow;
    size_t p1 = ((size_t)((bb * 2 + 1) * NH + h)) * NN + qrow;
    float s0 = Spart[p0], s1 = Spart[p1];
    float den = 1.0f / (s0 + s1);
    float w0 = s0 * den, w1 = s1 * den;
    h8 o0 = *(const h8*)(Opart + p0 * 32 + g * 8);
    h8 o1 = *(const h8*)(Opart + p1 * 32 + g * 8);
    h8 ah;
    #pragma unroll
    for (int j = 0; j < 8; j++)
      ah[j] = (_Float16)(w0 * (float)o0[j] + w1 * (float)o1[j]);
    h8 wh0 = *(const h8*)(whp0 + h * 32);
    h8 wh1 = *(const h8*)(whp1 + h * 32);
    acc0 = __builtin_amdgcn_mfma_f32_16x16x32_f16(ah, wh0, acc0, 0, 0, 0);
    acc1 = __builtin_amdgcn_mfma_f32_16x16x32_f16(ah, wh1, acc1, 0, 0, 0);
  }

  #pragma unroll
  for (int i = 0; i < 4; i++) {
    int m = m0 + w * 16 + 4 * g + i;
    int na = n0 + ml, nb = n0 + 16 + ml;
    Cf[(size_t)m * HD + na] = acc0[i] + bias[na] + resid[(size_t)m * HD + na];
    Cf[(size_t)m * HD + nb] = acc1[i] + bias[nb] + resid[(size_t)m * HD + nb];
  }
}

// ---------------- MFMA flash attention: 2 HEADS PER 512-THREAD BLOCK (r18 best) ----
__global__ __launch_bounds__(512) void attn_mfma_kernel(
    const _Float16* __restrict__ qkv16, const _Float16* __restrict__ vtb,
    const float* __restrict__ adj,
    _Float16* __restrict__ Opart, float* __restrict__ Spart)
{
  __shared__ _Float16 Ksh[2][2][64][40];  // [head][buf][kv][dim]   20.5 KB
  __shared__ _Float16 Vp[2][2][32][72];   // [head][buf][dim][kv']  18.4 KB
  __shared__ _Float16 AdjL[2][64][68];    // [buf][qrow][kv] shared 17.4 KB -> 55 KB

  const int z = blockIdx.z;                  // b*NSPLIT + half (0..3)
  const int b = z >> 1, half = z & 1;
  const int hg = blockIdx.y;                 // head group (0..3)
  const int q0 = blockIdx.x * 64;
  const int t = threadIdx.x;                 // 0..511
  const int hh_ = t >> 8;                    // which head within the block
  const int head = hg * 2 + hh_;
  const int tl = t & 255;
  const int w = tl >> 6, l = t & 63;
  const int m = l & 15, g = l >> 4;
  const int kvbase = half * KVPB;            // 1024 kv per block

  const int qrow = q0 + w * 16 + m;
  h8 qh = *(const h8*)(qkv16 + ((size_t)(b * NN + qrow)) * QKVLD + head * DH + g * 8);

  fx4 ot0 = {0.f, 0.f, 0.f, 0.f};
  fx4 ot1 = {0.f, 0.f, 0.f, 0.f};
  float S4[4] = {0.f, 0.f, 0.f, 0.f};

  // shared adj staging role: ALL 512 threads; thread t covers rows
  // {arow0, arow0+32}, col (t&15)*4 of the 64x64 tile (coalesced row-major)
  const int arow0 = t >> 4;                  // 0..31
  const int acol = (t & 15) * 4;
  const float* adjbase = adj + ((size_t)(b * NN + q0)) * NN + kvbase;

  const int krow = tl >> 2, kd0 = (tl & 3) * 8;   // K staging role (per head half)
  const int vdim = tl >> 3, vkc = (tl & 7) * 8;   // V' staging role
  const _Float16* kbase = qkv16 + ((size_t)(b * NN + kvbase + krow)) * QKVLD + 256 + head * DH + kd0;
  const _Float16* vbase = vtb + ((size_t)(b * HD + head * DH + vdim)) * NN + kvbase + vkc;

  h8 kreg = *(const h8*)kbase;
  h8 vreg = *(const h8*)vbase;

  // prologue: stage adj tile 0 + K/V tile 0 into buf0; issue K/V tile-1 loads
  {
    float4 ar[2];
    #pragma unroll
    for (int j = 0; j < 2; j++)
      ar[j] = *(const float4*)(adjbase + (size_t)(j * 32 + arow0) * NN + acol);
    #pragma unroll
    for (int j = 0; j < 2; j++) {
      h4 hh;
      hh[0] = (_Float16)ar[j].x; hh[1] = (_Float16)ar[j].y;
      hh[2] = (_Float16)ar[j].z; hh[3] = (_Float16)ar[j].w;
      *(h4*)&AdjL[0][j * 32 + arow0][acol] = hh;
    }
  }
  *(h8*)&Ksh[hh_][0][krow][kd0] = kreg;
  *(h8*)&Vp[hh_][0][vdim][vkc]  = vreg;
  kreg = *(const h8*)(kbase + (size_t)64 * QKVLD);
  vreg = *(const h8*)(vbase + 64);
  __syncthreads();

  for (int tt = 0; tt < NTILES; ++tt) {
    const int cur = tt & 1;

    // ---- issue next adj tile's coalesced loads (hide under compute) ----
    float4 ar[2];
    if (tt + 1 < NTILES) {
      #pragma unroll
      for (int j = 0; j < 2; j++)
        ar[j] = *(const float4*)(adjbase + (size_t)(j * 32 + arow0) * NN
                                 + (tt + 1) * 64 + acol);
    }

    // ---- QK^T for the 64-kv tile ----
    h8 kh0 = *(const h8*)&Ksh[hh_][cur][     m][g * 8];
    h8 kh1 = *(const h8*)&Ksh[hh_][cur][16 + m][g * 8];
    h8 kh2 = *(const h8*)&Ksh[hh_][cur][32 + m][g * 8];
    h8 kh3 = *(const h8*)&Ksh[hh_][cur][48 + m][g * 8];
    fx4 z4 = {0.f, 0.f, 0.f, 0.f};
    fx4 st[4];
    st[0] = __builtin_amdgcn_mfma_f32_16x16x32_f16(kh0, qh, z4, 0, 0, 0);
    st[1] = __builtin_amdgcn_mfma_f32_16x16x32_f16(kh1, qh, z4, 0, 0, 0);
    st[2] = __builtin_amdgcn_mfma_f32_16x16x32_f16(kh2, qh, z4, 0, 0, 0);
    st[3] = __builtin_amdgcn_mfma_f32_16x16x32_f16(kh3, qh, z4, 0, 0, 0);

    // ---- adj from shared LDS (h4 reads), static-max softmax ----
    float pv[16];
    #pragma unroll
    for (int p = 0; p < 4; p++) {
      h4 ah4 = *(const h4*)&AdjL[cur][w * 16 + m][p * 16 + g * 4];
      float ps = 0.f;
      #pragma unroll
      for (int i = 0; i < 4; i++) {
        float a = (float)ah4[i];
        float e = __builtin_amdgcn_exp2f(st[p][i] + C1A * a + C0A);
        float pp = (0.25f + 0.75f * a) * e;
        pv[p * 4 + i] = pp;
        ps += pp;
      }
      S4[p] += ps;
    }
    // pack P in pair-interleaved k-slot order
    h8 ph0, ph1;
    #pragma unroll
    for (int q2 = 0; q2 < 4; q2++) {
      ph0[2*q2]     = (_Float16)pv[q2];
      ph0[2*q2 + 1] = (_Float16)pv[4 + q2];
      ph1[2*q2]     = (_Float16)pv[8 + q2];
      ph1[2*q2 + 1] = (_Float16)pv[12 + q2];
    }

    // ---- PV from buf[cur] ----
    h8 v00 = *(const h8*)&Vp[hh_][cur][m][g * 8];
    h8 v01 = *(const h8*)&Vp[hh_][cur][m][32 + g * 8];
    h8 v10 = *(const h8*)&Vp[hh_][cur][16 + m][g * 8];
    h8 v11 = *(const h8*)&Vp[hh_][cur][16 + m][32 + g * 8];
    ot0 = __builtin_amdgcn_mfma_f32_16x16x32_f16(v00, ph0, ot0, 0, 0, 0);
    ot0 = __builtin_amdgcn_mfma_f32_16x16x32_f16(v01, ph1, ot0, 0, 0, 0);
    ot1 = __builtin_amdgcn_mfma_f32_16x16x32_f16(v10, ph0, ot1, 0, 0, 0);
    ot1 = __builtin_amdgcn_mfma_f32_16x16x32_f16(v11, ph1, ot1, 0, 0, 0);

    // ---- stage tile tt+1; issue tt+2 K/V loads ----
    if (tt + 1 < NTILES) {
      #pragma unroll
      for (int j = 0; j < 2; j++) {
        h4 hh;
        hh[0] = (_Float16)ar[j].x; hh[1] = (_Float16)ar[j].y;
        hh[2] = (_Float16)ar[j].z; hh[3] = (_Float16)ar[j].w;
        *(h4*)&AdjL[cur ^ 1][j * 32 + arow0][acol] = hh;
      }
      *(h8*)&Ksh[hh_][cur ^ 1][krow][kd0] = kreg;
      *(h8*)&Vp[hh_][cur ^ 1][vdim][vkc]  = vreg;
      if (tt + 2 < NTILES) {
        kreg = *(const h8*)(kbase + (size_t)((tt + 2) * 64) * QKVLD);
        vreg = *(const h8*)(vbase + (tt + 2) * 64);
      }
    }
    __syncthreads();
  }

  // denominator: tree-combine the 4 partials, then cross-lane reduce
  float S = (S4[0] + S4[1]) + (S4[2] + S4[3]);
  S += __shfl_xor(S, 16);
  S += __shfl_xor(S, 32);

  float is = 1.0f / S;
  size_t prow = ((size_t)(z * NH + head)) * NN + qrow;
  _Float16* po = Opart + prow * 32;
  h4 o0h, o1h;
  #pragma unroll
  for (int j = 0; j < 4; j++) {
    o0h[j] = (_Float16)(ot0[j] * is);
    o1h[j] = (_Float16)(ot1[j] * is);
  }
  *(h4*)(po + 4 * g)      = o0h;
  *(h4*)(po + 16 + 4 * g) = o1h;
  if (g == 0) Spart[prow] = S;
}

extern "C" void kernel_launch(void* const* d_in, const int* in_sizes, int n_in,
                              void* d_out, int out_size, void* d_ws, size_t ws_size,
                              hipStream_t stream)
{
  const float* hidden    = (const float*)d_in[0];
  const float* adjacency = (const float*)d_in[1];
  const float* wq  = (const float*)d_in[3];
  const float* bq  = (const float*)d_in[4];
  const float* wk  = (const float*)d_in[5];
  const float* bk  = (const float*)d_in[6];
  const float* wv  = (const float*)d_in[7];
  const float* bv  = (const float*)d_in[8];
  const float* wo  = (const float*)d_in[9];
  const float* bo  = (const float*)d_in[10];
  const float* g1  = (const float*)d_in[11];
  const float* b1  = (const float*)d_in[12];
  const float* g2  = (const float*)d_in[13];
  const float* b2  = (const float*)d_in[14];
  const float* wf1 = (const float*)d_in[15];
  const float* bf1 = (const float*)d_in[16];
  const float* wf2 = (const float*)d_in[17];
  const float* bf2 = (const float*)d_in[18];
  float* out = (float*)d_out;

  char* base = (char*)d_ws;
  const size_t MB = 1024 * 1024;
  _Float16* norm1h = (_Float16*)(base);          // [0,2)
  _Float16* qkv16  = (_Float16*)(base + 2*MB);   // [2,8): [4096][768]
  _Float16* vtb    = (_Float16*)(base + 8*MB);   // [8,10): [2][256][2048]
  float*    hid2   = (float*)(base + 12*MB);     // [12,16) f32
  // attn fp16 partials [16,20.2); ffah overlays [16,24) after WO consumed them:
  _Float16* Opart = (_Float16*)(base + 16*MB);   // 4.2 MB: [4][8][2048][32] fp16
  _Float16* ffah  = (_Float16*)(base + 16*MB);   // [16,24): [4096][1024]
  float* Spart = (float*)(base + 25*MB);         // 512 KB: [4][8][2048] f32
  _Float16* wtb = (_Float16*)(base + 26*MB);     // 1.5 MB weights
  _Float16* WtQKVh = wtb; wtb += 768 * 256;
  _Float16* WtOh   = wtb; wtb += 256 * 256;
  _Float16* WtF1h  = wtb; wtb += 1024 * 256;
  _Float16* WtF2h  = wtb; wtb += 256 * 1024;
  float* biasqkv = (float*)(base + 28*MB);

  // prep: weight transposes + bias concat + LN1 (blocks 769..1792)
  prep_kernel<<<1793, 256, 0, stream>>>(wq, wk, wv, wo, wf1, wf2, bq, bk, bv,
      hidden, g1, b1, WtQKVh, WtOh, WtF1h, WtF2h, biasqkv, norm1h);

  // fused QKV (NT=4, grid 768)
  gemm16_kernel<256, 4, 12, 0, 0, 2><<<768, 256, 0, stream>>>(
      norm1h, WtQKVh, biasqkv, nullptr, nullptr, qkv16, vtb, QKVLD);

  // 2-heads-per-block attention (r18 best): grid (32, 4, 4), 512 thr
  attn_mfma_kernel<<<dim3(NN / 64, NH / 2, BB * NSPLIT), 512, 0, stream>>>(
      qkv16, vtb, adjacency, Opart, Spart);

  // WO GEMM with fused split-KV combine (+ bias + residual)
  wo_fused_kernel<<<512, 256, 0, stream>>>(
      Opart, Spart, WtOh, bo, hidden, hid2);

  ln_kernel<<<NTOK / 4, 256, 0, stream>>>(hid2, g2, b2, norm1h);

  // FF1 (NT=4, grid 1024)
  gemm16_kernel<256, 4, 16, 1, 0, 1><<<1024, 256, 0, stream>>>(
      norm1h, WtF1h, bf1, nullptr, nullptr, ffah, nullptr, 1024);

  // FF2 (NT=2, grid 512)
  gemm16_kernel<1024, 2, 8, 0, 1, 0><<<512, 256, 0, stream>>>(
      ffah, WtF2h, bf2, hid2, out, nullptr, nullptr, 256);
}

// Round 22
// 112.709 us; speedup vs baseline: 1.0478x; 1.0319x over previous
//
#include <hip/hip_runtime.h>
#include <math.h>

#define BB 2
#define NN 2048
#define HD 256
#define NH 8
#define DH 32
#define NTOK (BB*NN)   // 4096
#define QKVLD 768      // fused qkv row stride (fp16)
#define NSPLIT 2       // split-KV ways
#define KVPB (NN/NSPLIT)   // 1024 kv per block
#define NTILES (KVPB/64)   // 16

typedef _Float16 h8 __attribute__((ext_vector_type(8)));
typedef _Float16 h4 __attribute__((ext_vector_type(4)));
typedef float fx4 __attribute__((ext_vector_type(4)));

#define LOG2E 1.4426950408889634f
#define SQ_LOG2 0.25503486f   // log2(e)/sqrt(32), folded into wq/bq
// static-max softmax: P = exp2(st + 2*LOG2E*a - LOG2E - 6); bounded by construction.
#define C1A (2.0f * LOG2E)
#define C0A (-(LOG2E + 6.0f))

// ---------------- LayerNorm row helper ----------------
__device__ __forceinline__ void ln_row(const float* __restrict__ x,
    const float* __restrict__ g, const float* __restrict__ bta,
    _Float16* __restrict__ yh, int row, int lane)
{
  const float* xr = x + (size_t)row * HD + lane * 4;
  float4 v = *(const float4*)xr;
  float s = v.x + v.y + v.z + v.w;
  #pragma unroll
  for (int off = 32; off > 0; off >>= 1) s += __shfl_xor(s, off);
  float mu = s * (1.0f / HD);
  float dx0 = v.x - mu, dx1 = v.y - mu, dx2 = v.z - mu, dx3 = v.w - mu;
  float ss = dx0*dx0 + dx1*dx1 + dx2*dx2 + dx3*dx3;
  #pragma unroll
  for (int off = 32; off > 0; off >>= 1) ss += __shfl_xor(ss, off);
  float rinv = rsqrtf(ss * (1.0f / HD) + 1e-5f);
  float4 gv = *(const float4*)(g   + lane * 4);
  float4 bv = *(const float4*)(bta + lane * 4);
  h4 hh;
  hh[0] = (_Float16)(dx0 * rinv * gv.x + bv.x);
  hh[1] = (_Float16)(dx1 * rinv * gv.y + bv.y);
  hh[2] = (_Float16)(dx2 * rinv * gv.z + bv.z);
  hh[3] = (_Float16)(dx3 * rinv * gv.w + bv.w);
  *(h4*)(yh + (size_t)row * HD + lane * 4) = hh;
}

__global__ __launch_bounds__(256) void ln_kernel(const float* __restrict__ x,
    const float* __restrict__ g, const float* __restrict__ bta,
    _Float16* __restrict__ yh)
{
  ln_row(x, g, bta, yh, blockIdx.x * 4 + (threadIdx.x >> 6), threadIdx.x & 63);
}

// ---------------- fused prep: weight transposes + bias concat + LN1 -------
__device__ __forceinline__ void do_transpose(const float* __restrict__ W,
    _Float16* __restrict__ Wh, int Nw, int rowoff, int ldout, float scale,
    int bx, int by, float (*tile)[33])
{
  int k0 = by * 32, n0 = bx * 32;
  int c = threadIdx.x & 31, r = threadIdx.x >> 5;   // r 0..7
  #pragma unroll
  for (int i = 0; i < 4; i++)
    tile[r + i * 8][c] = W[(size_t)(k0 + r + i * 8) * Nw + n0 + c];
  __syncthreads();
  #pragma unroll
  for (int i = 0; i < 4; i++) {
    int n = r + i * 8;
    Wh[(size_t)(rowoff + n0 + n) * ldout + k0 + c] = (_Float16)(tile[c][n] * scale);
  }
}

__global__ __launch_bounds__(256) void prep_kernel(
    const float* wq, const float* wk, const float* wv, const float* wo,
    const float* wf1, const float* wf2,
    const float* bq, const float* bk, const float* bv,
    const float* hidden, const float* g1, const float* b1,
    _Float16* WtQKVh, _Float16* WtOh, _Float16* WtF1h, _Float16* WtF2h,
    float* biasqkv, _Float16* norm1h)
{
  __shared__ float tile[32][33];
  int bid = blockIdx.x;
  if (bid < 64)        do_transpose(wq,  WtQKVh,  256,   0,  256, SQ_LOG2, bid & 7, bid >> 3, tile);
  else if (bid < 128)  do_transpose(wk,  WtQKVh,  256, 256,  256, 1.0f, (bid-64) & 7, (bid-64) >> 3, tile);
  else if (bid < 192)  do_transpose(wv,  WtQKVh,  256, 512,  256, 1.0f, (bid-128) & 7, (bid-128) >> 3, tile);
  else if (bid < 256)  do_transpose(wo,  WtOh,    256,   0,  256, 1.0f, (bid-192) & 7, (bid-192) >> 3, tile);
  else if (bid < 512)  do_transpose(wf1, WtF1h,  1024,   0,  256, 1.0f, (bid-256) & 31, (bid-256) >> 5, tile);
  else if (bid < 768)  do_transpose(wf2, WtF2h,   256,   0, 1024, 1.0f, (bid-512) & 7, (bid-512) >> 3, tile);
  else if (bid == 768) {
    #pragma unroll
    for (int j = 0; j < 3; j++) {
      int t = j * 256 + threadIdx.x;
      biasqkv[t] = (t < 256) ? bq[t] * SQ_LOG2 : (t < 512) ? bk[t - 256] : bv[t - 512];
    }
  } else {
    // LN1: blocks 769..1792 -> 4096 rows
    ln_row(hidden, g1, b1, norm1h, (bid - 769) * 4 + (threadIdx.x >> 6), threadIdx.x & 63);
  }
}

// ---------------- pure-fp16 MFMA GEMM, direct-fragment, XCD-bijective swizzle,
// 2-stage register pipeline ----
template<int KK, int NT, int NX, int ACT, int RES, int OM>
__global__ __launch_bounds__(256) void gemm16_kernel(
    const _Float16* __restrict__ Ah, const _Float16* __restrict__ Wh,
    const float* __restrict__ bias, const float* __restrict__ resid,
    float* __restrict__ Cf, _Float16* __restrict__ Ch,
    _Float16* __restrict__ vtb, int N)
{
  const int lin = blockIdx.x;
  const int qch = gridDim.x >> 3;
  const int wg = (lin & 7) * qch + (lin >> 3);   // bijective (nwg % 8 == 0)
  const int bx = wg % NX, by = wg / NX;
  const int n0 = bx * (NT * 16);
  const int m0 = by * 64;
  const int t = threadIdx.x, w = t >> 6, l = t & 63;
  const int ml = l & 15, g = l >> 4;
  const int mrow = m0 + w * 16 + ml;

  const _Float16* aph = Ah + (size_t)mrow * KK + g * 8;
  const _Float16* whp[NT];
  #pragma unroll
  for (int nt = 0; nt < NT; nt++)
    whp[nt] = Wh + (size_t)(n0 + nt * 16 + ml) * KK + g * 8;

  fx4 acc[NT];
  #pragma unroll
  for (int nt = 0; nt < NT; nt++) acc[nt] = (fx4){0.f, 0.f, 0.f, 0.f};

  // software pipeline: stage 0 loads
  h8 ah = *(const h8*)(aph);
  h8 wh[NT];
  #pragma unroll
  for (int nt = 0; nt < NT; nt++) wh[nt] = *(const h8*)(whp[nt]);

  #pragma unroll 2
  for (int k0 = 32; k0 <= KK; k0 += 32) {
    h8 ahn;
    h8 whn[NT];
    if (k0 < KK) {
      ahn = *(const h8*)(aph + k0);
      #pragma unroll
      for (int nt = 0; nt < NT; nt++) whn[nt] = *(const h8*)(whp[nt] + k0);
    }
    #pragma unroll
    for (int nt = 0; nt < NT; nt++)
      acc[nt] = __builtin_amdgcn_mfma_f32_16x16x32_f16(ah, wh[nt], acc[nt], 0, 0, 0);
    ah = ahn;
    #pragma unroll
    for (int nt = 0; nt < NT; nt++) wh[nt] = whn[nt];
  }

  #pragma unroll
  for (int nt = 0; nt < NT; nt++) {
    int n = n0 + nt * 16 + ml;
    float bv = bias[n];
    #pragma unroll
    for (int i = 0; i < 4; i++) {
      int m = m0 + w * 16 + 4 * g + i;
      float vv = acc[nt][i] + bv;
      if (ACT == 1) vv = 0.5f * vv * (1.0f + erff(vv * 0.70710678118654752f));
      if (RES)      vv += resid[(size_t)m * N + n];
      if (OM == 0) {
        Cf[(size_t)m * N + n] = vv;
      } else if (OM == 1) {
        Ch[(size_t)m * N + n] = (_Float16)vv;
      } else {   // OM == 2: qkv; V transposed with pair-interleaved kv index
        if (n < 512) Ch[(size_t)m * QKVLD + n] = (_Float16)vv;
        else {
          int dim = n - 512, kv = m & (NN - 1), bb = m >> 11;
          int kvp = (kv & ~31) | ((kv & 15) << 1) | ((kv >> 4) & 1);
          vtb[((size_t)(bb * HD + dim)) * NN + kvp] = (_Float16)vv;
        }
      }
    }
  }
}

// ---------------- WO GEMM with FUSED split-KV combine ----------------
__global__ __launch_bounds__(256) void wo_fused_kernel(
    const _Float16* __restrict__ Opart, const float* __restrict__ Spart,
    const _Float16* __restrict__ Wh, const float* __restrict__ bias,
    const float* __restrict__ resid, float* __restrict__ Cf)
{
  const int lin = blockIdx.x;                  // 512 blocks
  const int qch = gridDim.x >> 3;
  const int wg = (lin & 7) * qch + (lin >> 3);
  const int bx = wg & 7, by = wg >> 3;         // NX=8
  const int n0 = bx * 32;
  const int m0 = by * 64;
  const int t = threadIdx.x, w = t >> 6, l = t & 63;
  const int ml = l & 15, g = l >> 4;
  const int mrow = m0 + w * 16 + ml;
  const int bb = mrow >> 11, qrow = mrow & (NN - 1);

  const _Float16* whp0 = Wh + (size_t)(n0 + ml) * HD + g * 8;
  const _Float16* whp1 = Wh + (size_t)(n0 + 16 + ml) * HD + g * 8;

  fx4 acc0 = {0.f, 0.f, 0.f, 0.f};
  fx4 acc1 = {0.f, 0.f, 0.f, 0.f};

  #pragma unroll
  for (int h = 0; h < NH; h++) {
    size_t p0 = ((size_t)((bb * 2 + 0) * NH + h)) * NN + qrow;
    size_t p1 = ((size_t)((bb * 2 + 1) * NH + h)) * NN + qrow;
    float s0 = Spart[p0], s1 = Spart[p1];
    float den = 1.0f / (s0 + s1);
    float w0 = s0 * den, w1 = s1 * den;
    h8 o0 = *(const h8*)(Opart + p0 * 32 + g * 8);
    h8 o1 = *(const h8*)(Opart + p1 * 32 + g * 8);
    h8 ah;
    #pragma unroll
    for (int j = 0; j < 8; j++)
      ah[j] = (_Float16)(w0 * (float)o0[j] + w1 * (float)o1[j]);
    h8 wh0 = *(const h8*)(whp0 + h * 32);
    h8 wh1 = *(const h8*)(whp1 + h * 32);
    acc0 = __builtin_amdgcn_mfma_f32_16x16x32_f16(ah, wh0, acc0, 0, 0, 0);
    acc1 = __builtin_amdgcn_mfma_f32_16x16x32_f16(ah, wh1, acc1, 0, 0, 0);
  }

  #pragma unroll
  for (int i = 0; i < 4; i++) {
    int m = m0 + w * 16 + 4 * g + i;
    int na = n0 + ml, nb = n0 + 16 + ml;
    Cf[(size_t)m * HD + na] = acc0[i] + bias[na] + resid[(size_t)m * HD + na];
    Cf[(size_t)m * HD + nb] = acc1[i] + bias[nb] + resid[(size_t)m * HD + nb];
  }
}

// ---------------- MFMA flash attention: 2 HEADS PER 512-THREAD BLOCK (r18 best) ----
__global__ __launch_bounds__(512) void attn_mfma_kernel(
    const _Float16* __restrict__ qkv16, const _Float16* __restrict__ vtb,
    const float* __restrict__ adj,
    _Float16* __restrict__ Opart, float* __restrict__ Spart)
{
  __shared__ _Float16 Ksh[2][2][64][40];  // [head][buf][kv][dim]   20.5 KB
  __shared__ _Float16 Vp[2][2][32][72];   // [head][buf][dim][kv']  18.4 KB
  __shared__ _Float16 AdjL[2][64][68];    // [buf][qrow][kv] shared 17.4 KB -> 55 KB

  const int z = blockIdx.z;                  // b*NSPLIT + half (0..3)
  const int b = z >> 1, half = z & 1;
  const int hg = blockIdx.y;                 // head group (0..3)
  const int q0 = blockIdx.x * 64;
  const int t = threadIdx.x;                 // 0..511
  const int hh_ = t >> 8;                    // which head within the block
  const int head = hg * 2 + hh_;
  const int tl = t & 255;
  const int w = tl >> 6, l = t & 63;
  const int m = l & 15, g = l >> 4;
  const int kvbase = half * KVPB;            // 1024 kv per block

  const int qrow = q0 + w * 16 + m;
  h8 qh = *(const h8*)(qkv16 + ((size_t)(b * NN + qrow)) * QKVLD + head * DH + g * 8);

  fx4 ot0 = {0.f, 0.f, 0.f, 0.f};
  fx4 ot1 = {0.f, 0.f, 0.f, 0.f};
  float S4[4] = {0.f, 0.f, 0.f, 0.f};

  // shared adj staging role: ALL 512 threads; thread t covers rows
  // {arow0, arow0+32}, col (t&15)*4 of the 64x64 tile (coalesced row-major)
  const int arow0 = t >> 4;                  // 0..31
  const int acol = (t & 15) * 4;
  const float* adjbase = adj + ((size_t)(b * NN + q0)) * NN + kvbase;

  const int krow = tl >> 2, kd0 = (tl & 3) * 8;   // K staging role (per head half)
  const int vdim = tl >> 3, vkc = (tl & 7) * 8;   // V' staging role
  const _Float16* kbase = qkv16 + ((size_t)(b * NN + kvbase + krow)) * QKVLD + 256 + head * DH + kd0;
  const _Float16* vbase = vtb + ((size_t)(b * HD + head * DH + vdim)) * NN + kvbase + vkc;

  h8 kreg = *(const h8*)kbase;
  h8 vreg = *(const h8*)vbase;

  // prologue: stage adj tile 0 + K/V tile 0 into buf0; issue K/V tile-1 loads
  {
    float4 ar[2];
    #pragma unroll
    for (int j = 0; j < 2; j++)
      ar[j] = *(const float4*)(adjbase + (size_t)(j * 32 + arow0) * NN + acol);
    #pragma unroll
    for (int j = 0; j < 2; j++) {
      h4 hh;
      hh[0] = (_Float16)ar[j].x; hh[1] = (_Float16)ar[j].y;
      hh[2] = (_Float16)ar[j].z; hh[3] = (_Float16)ar[j].w;
      *(h4*)&AdjL[0][j * 32 + arow0][acol] = hh;
    }
  }
  *(h8*)&Ksh[hh_][0][krow][kd0] = kreg;
  *(h8*)&Vp[hh_][0][vdim][vkc]  = vreg;
  kreg = *(const h8*)(kbase + (size_t)64 * QKVLD);
  vreg = *(const h8*)(vbase + 64);
  __syncthreads();

  for (int tt = 0; tt < NTILES; ++tt) {
    const int cur = tt & 1;

    // ---- issue next adj tile's coalesced loads (hide under compute) ----
    float4 ar[2];
    if (tt + 1 < NTILES) {
      #pragma unroll
      for (int j = 0; j < 2; j++)
        ar[j] = *(const float4*)(adjbase + (size_t)(j * 32 + arow0) * NN
                                 + (tt + 1) * 64 + acol);
    }

    // ---- QK^T for the 64-kv tile ----
    h8 kh0 = *(const h8*)&Ksh[hh_][cur][     m][g * 8];
    h8 kh1 = *(const h8*)&Ksh[hh_][cur][16 + m][g * 8];
    h8 kh2 = *(const h8*)&Ksh[hh_][cur][32 + m][g * 8];
    h8 kh3 = *(const h8*)&Ksh[hh_][cur][48 + m][g * 8];
    fx4 z4 = {0.f, 0.f, 0.f, 0.f};
    fx4 st[4];
    st[0] = __builtin_amdgcn_mfma_f32_16x16x32_f16(kh0, qh, z4, 0, 0, 0);
    st[1] = __builtin_amdgcn_mfma_f32_16x16x32_f16(kh1, qh, z4, 0, 0, 0);
    st[2] = __builtin_amdgcn_mfma_f32_16x16x32_f16(kh2, qh, z4, 0, 0, 0);
    st[3] = __builtin_amdgcn_mfma_f32_16x16x32_f16(kh3, qh, z4, 0, 0, 0);

    // ---- adj from shared LDS (h4 reads), static-max softmax ----
    float pv[16];
    #pragma unroll
    for (int p = 0; p < 4; p++) {
      h4 ah4 = *(const h4*)&AdjL[cur][w * 16 + m][p * 16 + g * 4];
      float ps = 0.f;
      #pragma unroll
      for (int i = 0; i < 4; i++) {
        float a = (float)ah4[i];
        float e = __builtin_amdgcn_exp2f(st[p][i] + C1A * a + C0A);
        float pp = (0.25f + 0.75f * a) * e;
        pv[p * 4 + i] = pp;
        ps += pp;
      }
      S4[p] += ps;
    }
    // pack P in pair-interleaved k-slot order
    h8 ph0, ph1;
    #pragma unroll
    for (int q2 = 0; q2 < 4; q2++) {
      ph0[2*q2]     = (_Float16)pv[q2];
      ph0[2*q2 + 1] = (_Float16)pv[4 + q2];
      ph1[2*q2]     = (_Float16)pv[8 + q2];
      ph1[2*q2 + 1] = (_Float16)pv[12 + q2];
    }

    // ---- PV from buf[cur] ----
    h8 v00 = *(const h8*)&Vp[hh_][cur][m][g * 8];
    h8 v01 = *(const h8*)&Vp[hh_][cur][m][32 + g * 8];
    h8 v10 = *(const h8*)&Vp[hh_][cur][16 + m][g * 8];
    h8 v11 = *(const h8*)&Vp[hh_][cur][16 + m][32 + g * 8];
    ot0 = __builtin_amdgcn_mfma_f32_16x16x32_f16(v00, ph0, ot0, 0, 0, 0);
    ot0 = __builtin_amdgcn_mfma_f32_16x16x32_f16(v01, ph1, ot0, 0, 0, 0);
    ot1 = __builtin_amdgcn_mfma_f32_16x16x32_f16(v10, ph0, ot1, 0, 0, 0);
    ot1 = __builtin_amdgcn_mfma_f32_16x16x32_f16(v11, ph1, ot1, 0, 0, 0);

    // ---- stage tile tt+1; issue tt+2 K/V loads ----
    if (tt + 1 < NTILES) {
      #pragma unroll
      for (int j = 0; j < 2; j++) {
        h4 hh;
        hh[0] = (_Float16)ar[j].x; hh[1] = (_Float16)ar[j].y;
        hh[2] = (_Float16)ar[j].z; hh[3] = (_Float16)ar[j].w;
        *(h4*)&AdjL[cur ^ 1][j * 32 + arow0][acol] = hh;
      }
      *(h8*)&Ksh[hh_][cur ^ 1][krow][kd0] = kreg;
      *(h8*)&Vp[hh_][cur ^ 1][vdim][vkc]  = vreg;
      if (tt + 2 < NTILES) {
        kreg = *(const h8*)(kbase + (size_t)((tt + 2) * 64) * QKVLD);
        vreg = *(const h8*)(vbase + (tt + 2) * 64);
      }
    }
    __syncthreads();
  }

  // denominator: tree-combine the 4 partials, then cross-lane reduce
  float S = (S4[0] + S4[1]) + (S4[2] + S4[3]);
  S += __shfl_xor(S, 16);
  S += __shfl_xor(S, 32);

  float is = 1.0f / S;
  size_t prow = ((size_t)(z * NH + head)) * NN + qrow;
  _Float16* po = Opart + prow * 32;
  h4 o0h, o1h;
  #pragma unroll
  for (int j = 0; j < 4; j++) {
    o0h[j] = (_Float16)(ot0[j] * is);
    o1h[j] = (_Float16)(ot1[j] * is);
  }
  *(h4*)(po + 4 * g)      = o0h;
  *(h4*)(po + 16 + 4 * g) = o1h;
  if (g == 0) Spart[prow] = S;
}

extern "C" void kernel_launch(void* const* d_in, const int* in_sizes, int n_in,
                              void* d_out, int out_size, void* d_ws, size_t ws_size,
                              hipStream_t stream)
{
  const float* hidden    = (const float*)d_in[0];
  const float* adjacency = (const float*)d_in[1];
  const float* wq  = (const float*)d_in[3];
  const float* bq  = (const float*)d_in[4];
  const float* wk  = (const float*)d_in[5];
  const float* bk  = (const float*)d_in[6];
  const float* wv  = (const float*)d_in[7];
  const float* bv  = (const float*)d_in[8];
  const float* wo  = (const float*)d_in[9];
  const float* bo  = (const float*)d_in[10];
  const float* g1  = (const float*)d_in[11];
  const float* b1  = (const float*)d_in[12];
  const float* g2  = (const float*)d_in[13];
  const float* b2  = (const float*)d_in[14];
  const float* wf1 = (const float*)d_in[15];
  const float* bf1 = (const float*)d_in[16];
  const float* wf2 = (const float*)d_in[17];
  const float* bf2 = (const float*)d_in[18];
  float* out = (float*)d_out;

  char* base = (char*)d_ws;
  const size_t MB = 1024 * 1024;
  _Float16* norm1h = (_Float16*)(base);          // [0,2)
  _Float16* qkv16  = (_Float16*)(base + 2*MB);   // [2,8): [4096][768]
  _Float16* vtb    = (_Float16*)(base + 8*MB);   // [8,10): [2][256][2048]
  float*    hid2   = (float*)(base + 12*MB);     // [12,16) f32
  // attn fp16 partials [16,20.2); ffah overlays [16,24) after WO consumed them:
  _Float16* Opart = (_Float16*)(base + 16*MB);   // 4.2 MB: [4][8][2048][32] fp16
  _Float16* ffah  = (_Float16*)(base + 16*MB);   // [16,24): [4096][1024]
  float* Spart = (float*)(base + 25*MB);         // 512 KB: [4][8][2048] f32
  _Float16* wtb = (_Float16*)(base + 26*MB);     // 1.5 MB weights
  _Float16* WtQKVh = wtb; wtb += 768 * 256;
  _Float16* WtOh   = wtb; wtb += 256 * 256;
  _Float16* WtF1h  = wtb; wtb += 1024 * 256;
  _Float16* WtF2h  = wtb; wtb += 256 * 1024;
  float* biasqkv = (float*)(base + 28*MB);

  // prep: weight transposes + bias concat + LN1 (blocks 769..1792)
  prep_kernel<<<1793, 256, 0, stream>>>(wq, wk, wv, wo, wf1, wf2, bq, bk, bv,
      hidden, g1, b1, WtQKVh, WtOh, WtF1h, WtF2h, biasqkv, norm1h);

  // fused QKV (NT=4, grid 768)
  gemm16_kernel<256, 4, 12, 0, 0, 2><<<768, 256, 0, stream>>>(
      norm1h, WtQKVh, biasqkv, nullptr, nullptr, qkv16, vtb, QKVLD);

  // 2-heads-per-block attention (r18 best): grid (32, 4, 4), 512 thr
  attn_mfma_kernel<<<dim3(NN / 64, NH / 2, BB * NSPLIT), 512, 0, stream>>>(
      qkv16, vtb, adjacency, Opart, Spart);

  // WO GEMM with fused split-KV combine (+ bias + residual)
  wo_fused_kernel<<<512, 256, 0, stream>>>(
      Opart, Spart, WtOh, bo, hidden, hid2);

  ln_kernel<<<NTOK / 4, 256, 0, stream>>>(hid2, g2, b2, norm1h);

  // FF1 (NT=4, grid 1024)
  gemm16_kernel<256, 4, 16, 1, 0, 1><<<1024, 256, 0, stream>>>(
      norm1h, WtF1h, bf1, nullptr, nullptr, ffah, nullptr, 1024);

  // FF2: NT=4 (NX=4, grid 256) -> A-traffic halves 64->32 MB (the biggest
  // single GEMM stream). Tests traffic-bound vs occupancy-bound at 1 blk/CU.
  gemm16_kernel<1024, 4, 4, 0, 1, 0><<<256, 256, 0, stream>>>(
      ffah, WtF2h, bf2, hid2, out, nullptr, nullptr, 256);
}